// Round 16
// baseline (630.438 us; speedup 1.0000x reference)
//
#include <hip/hip_runtime.h>

// EdgeCNN (DynamicEdgeConv): N=20000, F=64, H=128, K=6 (incl self). All f32.
// ROUND-20: mlp W-amortization (knn path BYTE-IDENTICAL to verified R19).
//   Round-19 post-mortem: knn 431->386us, Occ 37.5%, MFMA 36% + VALU 47% =
//   83% combined -- the 2-phase skeleton's structural plateau (next step
//   would be an 8-phase counted-vmcnt port; deferred). Cheapest remaining
//   cost: mlp at ~105us launches 1 block/node -> 20000 x 128KB = 2.56GB of
//   W1/W2 re-reads (~75us of L2 BW). Fix: 8 nodes/block (2500 blocks),
//   f-outer/node-inner loops -> weight traffic /8; per-node fma order
//   BITWISE identical (ascending f, ascending hh) -> absmax unchanged.
//   LDS 38.2KB -> 4 blocks/CU; acc[8][6] = 48 regs, no spill @128 thr.

#define N_NODES 20000
#define FDIM 64
#define KNN 6
#define HID 128
#define N_PAD 20480
#define NTILES 625      // A-tiles: 20000/32 exactly
#define PREP_TILES 628  // B-side pad: 157 blocks x 4 B-tiles = 628 tiles
#define NBLK 157        // blocks per chunk (4 B-tiles, 8 waves each)
#define NCHUNK 3
#define TPC 209         // ceil(625/3); chunks cover 209/209/207 tiles
#define RPB 256
#define TILE_J 64
#define MAX_CHUNKS 10
#define MLP_NB 8        // nodes per mlp block (20000 = 2500 * 8 exactly)

typedef __attribute__((ext_vector_type(8))) short short8;
typedef __attribute__((ext_vector_type(16))) float f32x16;

#define MFMAB(A, B, C) __builtin_amdgcn_mfma_f32_32x32x16_bf16((A), (B), (C), 0, 0, 0)
#define ROFF(r) (((r) & 3) + 8 * ((r) >> 2))

// Sorted-ascending 6-slot insert; strict '<' => earlier (lower-j) candidate
// wins ties when scanned in ascending j, matching jax.lax.top_k stability.
#define INSERT_CAND(bd, bj, dv, jv) do {                                      \
  if ((dv) < bd[5]) {                                                         \
    const bool c0 = (dv) < bd[0], c1 = (dv) < bd[1], c2 = (dv) < bd[2];       \
    const bool c3 = (dv) < bd[3], c4 = (dv) < bd[4];                          \
    bd[5] = c4 ? bd[4] : (dv);              bj[5] = c4 ? bj[4] : (jv);        \
    bd[4] = c4 ? (c3 ? bd[3] : (dv)) : bd[4]; bj[4] = c4 ? (c3 ? bj[3] : (jv)) : bj[4]; \
    bd[3] = c3 ? (c2 ? bd[2] : (dv)) : bd[3]; bj[3] = c3 ? (c2 ? bj[2] : (jv)) : bj[3]; \
    bd[2] = c2 ? (c1 ? bd[1] : (dv)) : bd[2]; bj[2] = c2 ? (c1 ? bj[1] : (jv)) : bj[2]; \
    bd[1] = c1 ? (c0 ? bd[0] : (dv)) : bd[1]; bj[1] = c1 ? (c0 ? bj[0] : (jv)) : bj[1]; \
    bd[0] = c0 ? (dv) : bd[0];              bj[0] = c0 ? (jv) : bj[0];        \
  }                                                                           \
} while (0)

#define LEXLT(dv, jv, ds, js) (((dv) < (ds)) || ((dv) == (ds) && (jv) < (js)))
#define INSERT_TIE(bd, bj, dv, jv) do {                                       \
  if (LEXLT((dv), (jv), bd[5], bj[5])) {                                      \
    const bool c0 = LEXLT((dv), (jv), bd[0], bj[0]);                          \
    const bool c1 = LEXLT((dv), (jv), bd[1], bj[1]);                          \
    const bool c2 = LEXLT((dv), (jv), bd[2], bj[2]);                          \
    const bool c3 = LEXLT((dv), (jv), bd[3], bj[3]);                          \
    const bool c4 = LEXLT((dv), (jv), bd[4], bj[4]);                          \
    bd[5] = c4 ? bd[4] : (dv);              bj[5] = c4 ? bj[4] : (jv);        \
    bd[4] = c4 ? (c3 ? bd[3] : (dv)) : bd[4]; bj[4] = c4 ? (c3 ? bj[3] : (jv)) : bj[4]; \
    bd[3] = c3 ? (c2 ? bd[2] : (dv)) : bd[3]; bj[3] = c3 ? (c2 ? bj[2] : (jv)) : bj[3]; \
    bd[2] = c2 ? (c1 ? bd[1] : (dv)) : bd[2]; bj[2] = c2 ? (c1 ? bj[1] : (jv)) : bj[2]; \
    bd[1] = c1 ? (c0 ? bd[0] : (dv)) : bd[1]; bj[1] = c1 ? (c0 ? bj[0] : (jv)) : bj[1]; \
    bd[0] = c0 ? (dv) : bd[0];              bj[0] = c0 ? (jv) : bj[0];        \
  }                                                                           \
} while (0)

__device__ __forceinline__ f32x16 zero16() {
  f32x16 v;
#pragma unroll
  for (int i = 0; i < 16; ++i) v[i] = 0.f;
  return v;
}

__device__ __forceinline__ unsigned short bf16_rne(float x) {
  unsigned u = __float_as_uint(x);
  u += 0x7fffu + ((u >> 16) & 1u);
  return (unsigned short)(u >> 16);
}
__device__ __forceinline__ float bf16_tof(unsigned short h) {
  return __uint_as_float(((unsigned)h) << 16);
}

// Async global->LDS, 16B per lane: LDS dest = wave-uniform base + lane*16,
// global src per-lane (guide section 5 / m97 pattern).
__device__ __forceinline__ void gload_lds16(const void* g, void* l) {
  __builtin_amdgcn_global_load_lds(
      (const __attribute__((address_space(1))) void*)g,
      (__attribute__((address_space(3))) void*)l, 16, 0, 0);
}

// ---------------------------------------------------------------------------
// Prep: sq + exact 3-term bf16 split (x = a+b+c), fragment-major layout:
// element (tile, ks, lane=(khalf<<5)|row, j) at tile*2048 + ks*512 + lane*8+j
// with feature = ks*16 + khalf*8 + j. Tiles 625..627 zeroed (B-side pad).
// ---------------------------------------------------------------------------
__global__ void prep_kernel(const float* __restrict__ x, short* __restrict__ xa,
                            short* __restrict__ xb, short* __restrict__ xc,
                            float* __restrict__ sq) {
  const int n = blockIdx.x * blockDim.x + threadIdx.x;
  if (n >= PREP_TILES * 32) return;
  const int tile = n >> 5, row = n & 31;
  unsigned short a[FDIM], b[FDIM], c[FDIM];
  float s = 0.f;
  if (n < N_NODES) {
    const float4* r4 = (const float4*)(x + (size_t)n * FDIM);
#pragma unroll
    for (int q = 0; q < 16; ++q) {
      const float4 v = r4[q];
      const float vv[4] = {v.x, v.y, v.z, v.w};
#pragma unroll
      for (int e = 0; e < 4; ++e) {
        const float xv = vv[e];
        s = fmaf(xv, xv, s);
        const unsigned short ua = bf16_rne(xv);
        const float r1 = xv - bf16_tof(ua);      // exact
        const unsigned short ub = bf16_rne(r1);
        const float r2 = r1 - bf16_tof(ub);      // exact
        a[q * 4 + e] = ua; b[q * 4 + e] = ub; c[q * 4 + e] = bf16_rne(r2);
      }
    }
  } else {
#pragma unroll
    for (int f = 0; f < FDIM; ++f) { a[f] = 0; b[f] = 0; c[f] = 0; }
    s = __builtin_inff();
  }
  sq[n] = s;
#pragma unroll
  for (int ks = 0; ks < 4; ++ks) {
#pragma unroll
    for (int hh = 0; hh < 2; ++hh) {
      short8 va, vb, vc;
#pragma unroll
      for (int j = 0; j < 8; ++j) {
        const int f = ks * 16 + hh * 8 + j;
        va[j] = (short)a[f]; vb[j] = (short)b[f]; vc[j] = (short)c[f];
      }
      const size_t off = (size_t)tile * 2048 + ks * 512 + (size_t)((hh << 5) | row) * 8;
      *(short8*)(xa + off) = va;
      *(short8*)(xb + off) = vb;
      *(short8*)(xc + off) = vc;
    }
  }
}

// ---------------------------------------------------------------------------
// bf16 MFMA kNN scan (BYTE-IDENTICAL to verified round-19): 8-wave blocks;
// wave pair (wq, wq+4) shares B-tile and splits the chunk's A-range in half.
// ---------------------------------------------------------------------------
__device__ __forceinline__ void load_frag(const short* __restrict__ xa,
                                          const short* __restrict__ xb,
                                          const short* __restrict__ xc, int t,
                                          int lane, short8 (&Fa)[4],
                                          short8 (&Fb)[4], short8 (&Fc)[4]) {
  const size_t tb = (size_t)t * 2048 + (size_t)lane * 8;
#pragma unroll
  for (int ks = 0; ks < 4; ++ks) {
    Fa[ks] = *(const short8*)(xa + tb + ks * 512);
    Fb[ks] = *(const short8*)(xb + tb + ks * 512);
    Fc[ks] = *(const short8*)(xc + tb + ks * 512);
  }
}

// Selection: keys + depth-4 tree-min; on any improvement run the EXACT full
// INSERT_CAND ladder in ascending r (= ascending j) -- verified semantics.
__device__ __forceinline__ void do_select(const f32x16& acc,
                                          const float* __restrict__ sq, int t,
                                          int h, float (&bd)[KNN],
                                          int (&bj)[KNN]) {
  const int sbase = t * 32 + 4 * h;
  float4 S4[4];
#pragma unroll
  for (int g = 0; g < 4; ++g) S4[g] = *(const float4*)(sq + sbase + 8 * g);
  const float sqa[16] = {S4[0].x, S4[0].y, S4[0].z, S4[0].w,
                         S4[1].x, S4[1].y, S4[1].z, S4[1].w,
                         S4[2].x, S4[2].y, S4[2].z, S4[2].w,
                         S4[3].x, S4[3].y, S4[3].z, S4[3].w};
  float key[16];
#pragma unroll
  for (int r = 0; r < 16; ++r) key[r] = fmaf(-2.f, acc[r], sqa[r]);  // sq_j-2dot
  float m8[8];
#pragma unroll
  for (int r = 0; r < 8; ++r) m8[r] = fminf(key[r], key[r + 8]);
  float m4[4];
#pragma unroll
  for (int r = 0; r < 4; ++r) m4[r] = fminf(m8[r], m8[r + 4]);
  const float m2a = fminf(m4[0], m4[2]), m2b = fminf(m4[1], m4[3]);
  const float m = fminf(m2a, m2b);
  if (__any(m < bd[5])) {
    const int jbase = t * 32 + 4 * h;
#pragma unroll
    for (int r = 0; r < 16; ++r) { INSERT_CAND(bd, bj, key[r], jbase + ROFF(r)); }
  }
}

__device__ __forceinline__ void xmerge(float (&bd)[KNN], int (&bj)[KNN]) {
  float od[KNN];
  int oj[KNN];
#pragma unroll
  for (int k = 0; k < KNN; ++k) {
    od[k] = __shfl_xor(bd[k], 32);
    oj[k] = __shfl_xor(bj[k], 32);
  }
#pragma unroll
  for (int k = 0; k < KNN; ++k) INSERT_TIE(bd, bj, od[k], oj[k]);
}

__global__ __launch_bounds__(512, 4) void knn_bf16_kernel(
    const short* __restrict__ xa, const short* __restrict__ xb,
    const short* __restrict__ xc, const float* __restrict__ sq,
    float* __restrict__ cand_d, unsigned short* __restrict__ cand_js,
    int* __restrict__ knn_idx, int nchunks) {
  __shared__ __align__(16) short sa[2][2][2048];  // [set][half][tile]
  __shared__ __align__(16) short sb[2][2][2048];
  __shared__ __align__(16) short sc[2][2][2048];
  __shared__ float md[4][KNN][32];
  __shared__ int mj[4][KNN][32];
  const int tid = threadIdx.x;
  const int lane = tid & 63;
  const int w = tid >> 6;              // wave 0..7
  const int wq = w & 3;                // B-tile slot within block
  const int hw = w >> 2;               // A-half (0 or 1)
  const int ct = blockIdx.x * 4 + wq;  // B-tile 0..627 (>=625 pad)
  const int jc = blockIdx.y;           // chunk
  const int h = lane >> 5, col = lane & 31;

  // One B-tile (32 centers) resident in VGPRs (pair waves duplicate load).
  short8 Ba[4], Bb[4], Bc[4];
  load_frag(xa, xb, xc, ct, lane, Ba, Bb, Bc);

  float bd[KNN];
  int bj[KNN];
#pragma unroll
  for (int k = 0; k < KNN; ++k) { bd[k] = __builtin_inff(); bj[k] = 0; }

  const int tbeg = jc * TPC;
  int tend = tbeg + TPC;
  if (tend > NTILES) tend = NTILES;
  const int span = tend - tbeg;            // 207..209
  const int len0 = (span + 1) >> 1;        // half0 length (phase driver N0)
  const int len1 = span - len0;
  const int mylen = hw ? len1 : len0;      // wave-uniform
  const int rbeg = tbeg + (hw ? len0 : 0); // wave's A-range start
  const int N0 = len0;

  // Wave stages quarter wq (= ks slice wq) of ITS half's tile.
  const int wo = wq * 512;                 // short offset within tile
  const int la8 = lane * 8;

#define STAGE(set, idx)                                                       \
  do {                                                                        \
    const size_t tb_ = (size_t)(rbeg + (idx)) * 2048 + wo + la8;              \
    gload_lds16(xa + tb_, &sa[set][hw][wo]);                                  \
    gload_lds16(xb + tb_, &sb[set][hw][wo]);                                  \
    gload_lds16(xc + tb_, &sc[set][hw][wo]);                                  \
  } while (0)

// Per-tile chain order identical to verified: aa,ab,ba,ac,ca,bb per ks.
#define COMPUTE_TILE(set, accvar)                                             \
  do {                                                                        \
    accvar = zero16();                                                        \
    _Pragma("unroll")                                                         \
    for (int ks = 0; ks < 4; ++ks) {                                          \
      const int o_ = ks * 512 + la8;                                          \
      const short8 Aa = *(const short8*)(&sa[set][hw][o_]);                   \
      const short8 Ab = *(const short8*)(&sb[set][hw][o_]);                   \
      const short8 Ac = *(const short8*)(&sc[set][hw][o_]);                   \
      accvar = MFMAB(Aa, Ba[ks], accvar);                                     \
      accvar = MFMAB(Aa, Bb[ks], accvar);                                     \
      accvar = MFMAB(Ab, Ba[ks], accvar);                                     \
      accvar = MFMAB(Aa, Bc[ks], accvar);                                     \
      accvar = MFMAB(Ac, Ba[ks], accvar);                                     \
      accvar = MFMAB(Ab, Bb[ks], accvar);                                     \
    }                                                                         \
  } while (0)

  // Prologue (round-18 schedule, guards on mylen; len1 >= 103 so idx 0,1 ok).
  STAGE(0, 0);
  __syncthreads();
  if (1 < mylen) STAGE(1, 1);
  f32x16 acA, acB;
  COMPUTE_TILE(0, acA);
  __syncthreads();

  // Steady state: compute(t) overlaps select(t-1); selects ascending t.
  int i = 1;
  for (; i + 1 < N0; i += 2) {
    if (i + 1 < mylen) STAGE(0, i + 1);
    if (i < mylen) COMPUTE_TILE(1, acB);
    if (i - 1 < mylen) do_select(acA, sq, rbeg + i - 1, h, bd, bj);
    __syncthreads();
    if (i + 2 < mylen) STAGE(1, i + 2);
    if (i + 1 < mylen) COMPUTE_TILE(0, acA);
    if (i < mylen) do_select(acB, sq, rbeg + i, h, bd, bj);
    __syncthreads();
  }
  if (i < N0) {  // N0 even: trailing phase; set1 holds tile i if valid
    if (i < mylen) COMPUTE_TILE(1, acB);
    if (i - 1 < mylen) do_select(acA, sq, rbeg + i - 1, h, bd, bj);
    if (i < mylen) do_select(acB, sq, rbeg + i, h, bd, bj);
  } else {       // N0 odd: only acA (tile N0-1) may be pending
    if (i - 1 < mylen) do_select(acA, sq, rbeg + i - 1, h, bd, bj);
  }
#undef STAGE
#undef COMPUTE_TILE

  // Merge the two row-halves (lane <-> lane^32) lexicographically.
  xmerge(bd, bj);

  // Pair merge: half-1 waves publish, half-0 waves fold (INSERT_TIE is
  // order-independent; same semantics as the chunk merge).
  __syncthreads();
  if (hw == 1 && h == 0) {
#pragma unroll
    for (int k = 0; k < KNN; ++k) {
      md[wq][k][col] = bd[k];
      mj[wq][k][col] = bj[k];
    }
  }
  __syncthreads();
  if (hw == 0 && h == 0) {
#pragma unroll
    for (int k = 0; k < KNN; ++k) {
      const float dv = md[wq][k][col];
      const int jv = mj[wq][k][col];
      INSERT_TIE(bd, bj, dv, jv);
    }
    const int i0 = ct * 32 + col;  // >= 20000 only for pad tiles 625..627
    if (i0 < N_NODES) {
      if (nchunks == 1) {
#pragma unroll
        for (int k = 0; k < KNN; ++k) knn_idx[(size_t)i0 * KNN + k] = bj[k];
      } else {
#pragma unroll
        for (int k = 0; k < KNN; ++k) {
          const size_t off = ((size_t)jc * KNN + k) * N_PAD + i0;
          cand_d[off] = bd[k];
          cand_js[off] = (unsigned short)bj[k];
        }
      }
    }
  }
}

// Merge u16-j chunk candidates (ascending jc = ascending j ranges preserves
// the lowest-j-wins tie discipline; per-chunk lists already sorted asc).
__global__ void knn_merge_u16_kernel(const float* __restrict__ cand_d,
                                     const unsigned short* __restrict__ cand_js,
                                     int* __restrict__ knn_idx, int nchunks) {
  const int i = blockIdx.x * blockDim.x + threadIdx.x;
  if (i >= N_NODES) return;
  float bd[KNN];
  int bj[KNN];
#pragma unroll
  for (int k = 0; k < KNN; ++k) { bd[k] = __builtin_inff(); bj[k] = 0; }
  for (int jc = 0; jc < nchunks; ++jc) {
#pragma unroll
    for (int k = 0; k < KNN; ++k) {
      const size_t off = ((size_t)jc * KNN + k) * N_PAD + i;
      const float d = cand_d[off];
      const int j = (int)cand_js[off];
      INSERT_CAND(bd, bj, d, j);
    }
  }
#pragma unroll
  for (int k = 0; k < KNN; ++k) knn_idx[(size_t)i * KNN + k] = bj[k];
}

// ---------------------------------------------------------------------------
// Fallback VALU path (proven round-4) -- tiny-ws only.
// ---------------------------------------------------------------------------
__global__ void sq_kernel(const float* __restrict__ x, float* __restrict__ sq) {
  const int i = blockIdx.x * blockDim.x + threadIdx.x;
  if (i >= N_NODES) return;
  const float4* r4 = (const float4*)(x + (size_t)i * FDIM);
  float s = 0.f;
#pragma unroll
  for (int q = 0; q < 16; ++q) {
    const float4 a = r4[q];
    s = fmaf(a.x, a.x, s);
    s = fmaf(a.y, a.y, s);
    s = fmaf(a.z, a.z, s);
    s = fmaf(a.w, a.w, s);
  }
  sq[i] = s;
}

__global__ __launch_bounds__(RPB, 2) void knn_partial_kernel(
    const float* __restrict__ x, const float* __restrict__ sq,
    float* __restrict__ cand_d, int* __restrict__ cand_j,
    int* __restrict__ knn_idx, int jchunk, int nchunks) {
  __shared__ __align__(16) float xs[TILE_J][FDIM + 4];
  __shared__ float sqs[TILE_J];
  const int tid = threadIdx.x;
  const int i = blockIdx.x * RPB + tid;
  const bool valid = i < N_NODES;
  const int jc = blockIdx.y;

  float xi[FDIM];
  float sqi = 0.f;
  if (valid) {
    const float4* r4 = (const float4*)(x + (size_t)i * FDIM);
#pragma unroll
    for (int q = 0; q < 16; ++q) {
      const float4 a = r4[q];
      xi[q * 4 + 0] = a.x; xi[q * 4 + 1] = a.y;
      xi[q * 4 + 2] = a.z; xi[q * 4 + 3] = a.w;
    }
    sqi = sq[i];
  } else {
#pragma unroll
    for (int f = 0; f < FDIM; ++f) xi[f] = 0.f;
  }
#pragma unroll
  for (int f = 0; f < FDIM; ++f) asm volatile("" : "+v"(xi[f]));

  float bd[KNN];
  int bj[KNN];
#pragma unroll
  for (int k = 0; k < KNN; ++k) { bd[k] = __builtin_inff(); bj[k] = 0; }

  const int jcbase = jc * jchunk;
  for (int t0 = 0; t0 < jchunk; t0 += TILE_J) {
    const int jt = jcbase + t0;
    __syncthreads();
    {
      const int jj = tid >> 2;
      const int f0 = (tid & 3) * 16;
      const int j = jt + jj;
      float4* dst = (float4*)&xs[jj][f0];
      if (j < N_NODES) {
        const float4* src = (const float4*)(x + (size_t)j * FDIM + f0);
        dst[0] = src[0];
        dst[1] = src[1];
        dst[2] = src[2];
        dst[3] = src[3];
      } else {
        const float4 z = make_float4(0.f, 0.f, 0.f, 0.f);
        dst[0] = z; dst[1] = z; dst[2] = z; dst[3] = z;
      }
      if (tid < TILE_J) {
        const int j2 = jt + tid;
        sqs[tid] = (j2 < N_NODES) ? sq[j2] : 0.f;
      }
    }
    __syncthreads();
    const int rem = N_NODES - jt;
    const int jmax = rem < TILE_J ? rem : TILE_J;
    for (int jj = 0; jj < jmax; ++jj) {
      const float4* xr4 = (const float4*)&xs[jj][0];
      float dot = 0.f;
#pragma unroll
      for (int q = 0; q < 16; ++q) {
        const float4 v = xr4[q];
        dot = fmaf(xi[q * 4 + 0], v.x, dot);
        dot = fmaf(xi[q * 4 + 1], v.y, dot);
        dot = fmaf(xi[q * 4 + 2], v.z, dot);
        dot = fmaf(xi[q * 4 + 3], v.w, dot);
      }
      const float d = fmaf(-2.f, dot, sqi + sqs[jj]);
      const int j = jt + jj;
      INSERT_CAND(bd, bj, d, j);
    }
  }

  if (valid) {
    if (nchunks == 1) {
#pragma unroll
      for (int k = 0; k < KNN; ++k) knn_idx[(size_t)i * KNN + k] = bj[k];
    } else {
#pragma unroll
      for (int k = 0; k < KNN; ++k) {
        const size_t off = ((size_t)jc * KNN + k) * N_PAD + i;
        cand_d[off] = bd[k];
        cand_j[off] = bj[k];
      }
    }
  }
}

__global__ void knn_merge_kernel(const float* __restrict__ cand_d,
                                 const int* __restrict__ cand_j,
                                 int* __restrict__ knn_idx, int nchunks) {
  const int i = blockIdx.x * blockDim.x + threadIdx.x;
  if (i >= N_NODES) return;
  float bd[KNN];
  int bj[KNN];
#pragma unroll
  for (int k = 0; k < KNN; ++k) { bd[k] = __builtin_inff(); bj[k] = 0; }
  for (int jc = 0; jc < nchunks; ++jc) {
#pragma unroll
    for (int k = 0; k < KNN; ++k) {
      const size_t off = ((size_t)jc * KNN + k) * N_PAD + i;
      const float d = cand_d[off];
      const int j = cand_j[off];
      INSERT_CAND(bd, bj, d, j);
    }
  }
#pragma unroll
  for (int k = 0; k < KNN; ++k) knn_idx[(size_t)i * KNN + k] = bj[k];
}

// ---------------------------------------------------------------------------
// MLP: 8 nodes per block -- W1/W2 read once per block (traffic /8).
// Per-node fma order BITWISE identical to the verified single-node mlp.
// ---------------------------------------------------------------------------
__global__ __launch_bounds__(HID) void mlp8_kernel(
    const float* __restrict__ x, const int* __restrict__ knn_idx,
    const float* __restrict__ W1, const float* __restrict__ b1,
    const float* __restrict__ W2, const float* __restrict__ b2,
    float* __restrict__ out) {
  __shared__ float xi_s[MLP_NB][FDIM];
  __shared__ float xd_s[MLP_NB][KNN][FDIM];
  __shared__ float h1_s[MLP_NB][KNN][HID];
  __shared__ int nb[MLP_NB][KNN];
  const int nbase = blockIdx.x * MLP_NB;  // 20000 = 2500*8 exactly
  const int t = threadIdx.x;              // output channel

  if (t < MLP_NB * KNN) {  // 48 < 128
    const int n = t / KNN, k = t % KNN;
    const int v = knn_idx[(size_t)(nbase + n) * KNN + k];
    nb[n][k] = ((unsigned)v < (unsigned)N_NODES) ? v : 0;  // clamp
  }
#pragma unroll
  for (int e = t; e < MLP_NB * FDIM; e += HID) {  // 4 iters
    const int n = e >> 6, f = e & 63;
    xi_s[n][f] = x[(size_t)(nbase + n) * FDIM + f];
  }
  __syncthreads();
  for (int e = t; e < MLP_NB * KNN * FDIM; e += HID) {  // 24 iters
    const int n = e / (KNN * FDIM);
    const int rem = e - n * (KNN * FDIM);
    const int k = rem >> 6, f = rem & 63;
    xd_s[n][k][f] = x[(size_t)nb[n][k] * FDIM + f] - xi_s[n][f];
  }
  __syncthreads();

  // Layer 1: s0[n] = b1 + sum_f xi*W1 (ascending f, same chain per node).
  float s0[MLP_NB];
#pragma unroll
  for (int n = 0; n < MLP_NB; ++n) s0[n] = b1[t];
  for (int f = 0; f < FDIM; ++f) {
    const float wv = W1[f * HID + t];
#pragma unroll
    for (int n = 0; n < MLP_NB; ++n) s0[n] = fmaf(xi_s[n][f], wv, s0[n]);
  }
  float acc[MLP_NB][KNN];
#pragma unroll
  for (int n = 0; n < MLP_NB; ++n)
#pragma unroll
    for (int k = 0; k < KNN; ++k) acc[n][k] = s0[n];
  for (int f = 0; f < FDIM; ++f) {
    const float wv = W1[(FDIM + f) * HID + t];
#pragma unroll
    for (int n = 0; n < MLP_NB; ++n)
#pragma unroll
      for (int k = 0; k < KNN; ++k)
        acc[n][k] = fmaf(xd_s[n][k][f], wv, acc[n][k]);
  }
#pragma unroll
  for (int n = 0; n < MLP_NB; ++n)
#pragma unroll
    for (int k = 0; k < KNN; ++k) h1_s[n][k][t] = fmaxf(acc[n][k], 0.f);
  __syncthreads();

  // Layer 2 (no relu) + max aggregation (ascending hh, same chain per node).
  float acc2[MLP_NB][KNN];
  const float bb = b2[t];
#pragma unroll
  for (int n = 0; n < MLP_NB; ++n)
#pragma unroll
    for (int k = 0; k < KNN; ++k) acc2[n][k] = bb;
  for (int hh = 0; hh < HID; ++hh) {
    const float wv = W2[hh * HID + t];
#pragma unroll
    for (int n = 0; n < MLP_NB; ++n)
#pragma unroll
      for (int k = 0; k < KNN; ++k)
        acc2[n][k] = fmaf(h1_s[n][k][hh], wv, acc2[n][k]);
  }
#pragma unroll
  for (int n = 0; n < MLP_NB; ++n) {
    float m = acc2[n][0];
#pragma unroll
    for (int k = 1; k < KNN; ++k) m = fmaxf(m, acc2[n][k]);
    out[(size_t)(nbase + n) * HID + t] = m;
  }
}

extern "C" void kernel_launch(void* const* d_in, const int* in_sizes, int n_in,
                              void* d_out, int out_size, void* d_ws, size_t ws_size,
                              hipStream_t stream) {
  const float* x  = (const float*)d_in[0];
  const float* W1 = (const float*)d_in[2];
  const float* b1 = (const float*)d_in[3];
  const float* W2 = (const float*)d_in[4];
  const float* b2 = (const float*)d_in[5];
  float* out = (float*)d_out;
  char* ws = (char*)d_ws;
  const size_t PER_CHUNK = (size_t)KNN * N_PAD * 8;  // 983,040 B (fallback)

  if (ws_size >= 0x998000) {
    // MFMA layout (10,059,776 B required; inferred ws >= 10,420,224):
    //   0x000000 sq      (20096 f32 used; 0x20000 reserved)
    //   0x020000 xa      (628*2048 s16 = 2,572,288 B) -> 0x294000
    //   0x294000 xb      -> 0x508000
    //   0x508000 xc      -> 0x77C000
    //   0x77C000 cand_d  (3*6*20480 f32 = 1,474,560 B) -> 0x8E4000
    //   0x8E4000 cand_js (3*6*20480 u16 = 737,280 B)  -> 0x998000
    //   knn aliases xa at 0x20000 (xa dead after the scan).
    float* sq   = (float*)ws;
    short* xa   = (short*)(ws + 0x20000);
    short* xb   = (short*)(ws + 0x294000);
    short* xc   = (short*)(ws + 0x508000);
    float* cand_d = (float*)(ws + 0x77C000);
    unsigned short* cand_js = (unsigned short*)(ws + 0x8E4000);
    int* knn = (int*)(ws + 0x20000);

    prep_kernel<<<dim3((PREP_TILES * 32 + 255) / 256), dim3(256), 0, stream>>>(
        x, xa, xb, xc, sq);
    knn_bf16_kernel<<<dim3(NBLK, NCHUNK), dim3(512), 0, stream>>>(
        xa, xb, xc, sq, cand_d, cand_js, knn, NCHUNK);
    knn_merge_u16_kernel<<<dim3((N_NODES + 255) / 256), dim3(256), 0, stream>>>(
        cand_d, cand_js, knn, NCHUNK);
    mlp8_kernel<<<dim3(N_NODES / MLP_NB), dim3(HID), 0, stream>>>(
        x, knn, W1, b1, W2, b2, out);
  } else {
    // Fallback: round-4 layout (sq | knn | cand at 0x90000)
    float* sq = (float*)ws;
    int* knn  = (int*)(ws + (size_t)N_PAD * 4);
    const size_t BASE = 0x90000;
    int nc = 1;
    if (ws_size > BASE + PER_CHUNK) {
      size_t fit = (ws_size - BASE) / PER_CHUNK;
      nc = fit < (size_t)MAX_CHUNKS ? (int)fit : MAX_CHUNKS;
      if (nc < 1) nc = 1;
    }
    int jchunk = ((N_NODES + nc - 1) / nc + TILE_J - 1) / TILE_J * TILE_J;
    float* cand_d = (float*)(ws + BASE);
    int* cand_j = (int*)(ws + BASE + (size_t)nc * KNN * N_PAD * 4);

    sq_kernel<<<dim3((N_NODES + 255) / 256), dim3(256), 0, stream>>>(x, sq);
    knn_partial_kernel<<<dim3((N_NODES + RPB - 1) / RPB, nc), dim3(RPB), 0, stream>>>(
        x, sq, cand_d, cand_j, knn, jchunk, nc);
    if (nc > 1) {
      knn_merge_kernel<<<dim3((N_NODES + 255) / 256), dim3(256), 0, stream>>>(
          cand_d, cand_j, knn, nc);
    }
    mlp8_kernel<<<dim3(N_NODES / MLP_NB), dim3(HID), 0, stream>>>(
        x, knn, W1, b1, W2, b2, out);
  }
}

// Round 18
// 586.161 us; speedup vs baseline: 1.0755x; 1.0755x over previous
//
#include <hip/hip_runtime.h>

// EdgeCNN (DynamicEdgeConv): N=20000, F=64, H=128, K=6 (incl self). All f32.
// ROUND-22: RESUBMIT of round-21 (bench infra failed twice: no kernel
// signal; do not mutate on an environmental flake -- round-8 precedent).
//   Round-20 post-mortem: MLP_NB=8 REGRESSED (+73us): acc[8][6]=48 live regs
//   + 48 LDS-addr per f-iter in a 128-thread block = the spill regime this
//   toolchain showed twice (VGPR pinning), and 39KB LDS cut blocks/CU 8->4.
//   Fix: MLP_NB=4 -- weight traffic /4 (captures ~75% of the waste), acc 24
//   regs (peak live ~60, no spill at any pin), LDS 19.6KB -> 8 blocks/CU.
//   Per-node fma order bitwise identical (proved absmax 0.0 in round-20).
//   knn path BYTE-IDENTICAL to verified round-19 (386us, MfmaUtil 36%).

#define N_NODES 20000
#define FDIM 64
#define KNN 6
#define HID 128
#define N_PAD 20480
#define NTILES 625      // A-tiles: 20000/32 exactly
#define PREP_TILES 628  // B-side pad: 157 blocks x 4 B-tiles = 628 tiles
#define NBLK 157        // blocks per chunk (4 B-tiles, 8 waves each)
#define NCHUNK 3
#define TPC 209         // ceil(625/3); chunks cover 209/209/207 tiles
#define RPB 256
#define TILE_J 64
#define MAX_CHUNKS 10
#define MLP_NB 4        // nodes per mlp block (20000 = 5000 * 4 exactly)

typedef __attribute__((ext_vector_type(8))) short short8;
typedef __attribute__((ext_vector_type(16))) float f32x16;

#define MFMAB(A, B, C) __builtin_amdgcn_mfma_f32_32x32x16_bf16((A), (B), (C), 0, 0, 0)
#define ROFF(r) (((r) & 3) + 8 * ((r) >> 2))

// Sorted-ascending 6-slot insert; strict '<' => earlier (lower-j) candidate
// wins ties when scanned in ascending j, matching jax.lax.top_k stability.
#define INSERT_CAND(bd, bj, dv, jv) do {                                      \
  if ((dv) < bd[5]) {                                                         \
    const bool c0 = (dv) < bd[0], c1 = (dv) < bd[1], c2 = (dv) < bd[2];       \
    const bool c3 = (dv) < bd[3], c4 = (dv) < bd[4];                          \
    bd[5] = c4 ? bd[4] : (dv);              bj[5] = c4 ? bj[4] : (jv);        \
    bd[4] = c4 ? (c3 ? bd[3] : (dv)) : bd[4]; bj[4] = c4 ? (c3 ? bj[3] : (jv)) : bj[4]; \
    bd[3] = c3 ? (c2 ? bd[2] : (dv)) : bd[3]; bj[3] = c3 ? (c2 ? bj[2] : (jv)) : bj[3]; \
    bd[2] = c2 ? (c1 ? bd[1] : (dv)) : bd[2]; bj[2] = c2 ? (c1 ? bj[1] : (jv)) : bj[2]; \
    bd[1] = c1 ? (c0 ? bd[0] : (dv)) : bd[1]; bj[1] = c1 ? (c0 ? bj[0] : (jv)) : bj[1]; \
    bd[0] = c0 ? (dv) : bd[0];              bj[0] = c0 ? (jv) : bj[0];        \
  }                                                                           \
} while (0)

#define LEXLT(dv, jv, ds, js) (((dv) < (ds)) || ((dv) == (ds) && (jv) < (js)))
#define INSERT_TIE(bd, bj, dv, jv) do {                                       \
  if (LEXLT((dv), (jv), bd[5], bj[5])) {                                      \
    const bool c0 = LEXLT((dv), (jv), bd[0], bj[0]);                          \
    const bool c1 = LEXLT((dv), (jv), bd[1], bj[1]);                          \
    const bool c2 = LEXLT((dv), (jv), bd[2], bj[2]);                          \
    const bool c3 = LEXLT((dv), (jv), bd[3], bj[3]);                          \
    const bool c4 = LEXLT((dv), (jv), bd[4], bj[4]);                          \
    bd[5] = c4 ? bd[4] : (dv);              bj[5] = c4 ? bj[4] : (jv);        \
    bd[4] = c4 ? (c3 ? bd[3] : (dv)) : bd[4]; bj[4] = c4 ? (c3 ? bj[3] : (jv)) : bj[4]; \
    bd[3] = c3 ? (c2 ? bd[2] : (dv)) : bd[3]; bj[3] = c3 ? (c2 ? bj[2] : (jv)) : bj[3]; \
    bd[2] = c2 ? (c1 ? bd[1] : (dv)) : bd[2]; bj[2] = c2 ? (c1 ? bj[1] : (jv)) : bj[2]; \
    bd[1] = c1 ? (c0 ? bd[0] : (dv)) : bd[1]; bj[1] = c1 ? (c0 ? bj[0] : (jv)) : bj[1]; \
    bd[0] = c0 ? (dv) : bd[0];              bj[0] = c0 ? (jv) : bj[0];        \
  }                                                                           \
} while (0)

__device__ __forceinline__ f32x16 zero16() {
  f32x16 v;
#pragma unroll
  for (int i = 0; i < 16; ++i) v[i] = 0.f;
  return v;
}

__device__ __forceinline__ unsigned short bf16_rne(float x) {
  unsigned u = __float_as_uint(x);
  u += 0x7fffu + ((u >> 16) & 1u);
  return (unsigned short)(u >> 16);
}
__device__ __forceinline__ float bf16_tof(unsigned short h) {
  return __uint_as_float(((unsigned)h) << 16);
}

// Async global->LDS, 16B per lane: LDS dest = wave-uniform base + lane*16,
// global src per-lane (guide section 5 / m97 pattern).
__device__ __forceinline__ void gload_lds16(const void* g, void* l) {
  __builtin_amdgcn_global_load_lds(
      (const __attribute__((address_space(1))) void*)g,
      (__attribute__((address_space(3))) void*)l, 16, 0, 0);
}

// ---------------------------------------------------------------------------
// Prep: sq + exact 3-term bf16 split (x = a+b+c), fragment-major layout:
// element (tile, ks, lane=(khalf<<5)|row, j) at tile*2048 + ks*512 + lane*8+j
// with feature = ks*16 + khalf*8 + j. Tiles 625..627 zeroed (B-side pad).
// ---------------------------------------------------------------------------
__global__ void prep_kernel(const float* __restrict__ x, short* __restrict__ xa,
                            short* __restrict__ xb, short* __restrict__ xc,
                            float* __restrict__ sq) {
  const int n = blockIdx.x * blockDim.x + threadIdx.x;
  if (n >= PREP_TILES * 32) return;
  const int tile = n >> 5, row = n & 31;
  unsigned short a[FDIM], b[FDIM], c[FDIM];
  float s = 0.f;
  if (n < N_NODES) {
    const float4* r4 = (const float4*)(x + (size_t)n * FDIM);
#pragma unroll
    for (int q = 0; q < 16; ++q) {
      const float4 v = r4[q];
      const float vv[4] = {v.x, v.y, v.z, v.w};
#pragma unroll
      for (int e = 0; e < 4; ++e) {
        const float xv = vv[e];
        s = fmaf(xv, xv, s);
        const unsigned short ua = bf16_rne(xv);
        const float r1 = xv - bf16_tof(ua);      // exact
        const unsigned short ub = bf16_rne(r1);
        const float r2 = r1 - bf16_tof(ub);      // exact
        a[q * 4 + e] = ua; b[q * 4 + e] = ub; c[q * 4 + e] = bf16_rne(r2);
      }
    }
  } else {
#pragma unroll
    for (int f = 0; f < FDIM; ++f) { a[f] = 0; b[f] = 0; c[f] = 0; }
    s = __builtin_inff();
  }
  sq[n] = s;
#pragma unroll
  for (int ks = 0; ks < 4; ++ks) {
#pragma unroll
    for (int hh = 0; hh < 2; ++hh) {
      short8 va, vb, vc;
#pragma unroll
      for (int j = 0; j < 8; ++j) {
        const int f = ks * 16 + hh * 8 + j;
        va[j] = (short)a[f]; vb[j] = (short)b[f]; vc[j] = (short)c[f];
      }
      const size_t off = (size_t)tile * 2048 + ks * 512 + (size_t)((hh << 5) | row) * 8;
      *(short8*)(xa + off) = va;
      *(short8*)(xb + off) = vb;
      *(short8*)(xc + off) = vc;
    }
  }
}

// ---------------------------------------------------------------------------
// bf16 MFMA kNN scan (BYTE-IDENTICAL to verified round-19): 8-wave blocks;
// wave pair (wq, wq+4) shares B-tile and splits the chunk's A-range in half.
// ---------------------------------------------------------------------------
__device__ __forceinline__ void load_frag(const short* __restrict__ xa,
                                          const short* __restrict__ xb,
                                          const short* __restrict__ xc, int t,
                                          int lane, short8 (&Fa)[4],
                                          short8 (&Fb)[4], short8 (&Fc)[4]) {
  const size_t tb = (size_t)t * 2048 + (size_t)lane * 8;
#pragma unroll
  for (int ks = 0; ks < 4; ++ks) {
    Fa[ks] = *(const short8*)(xa + tb + ks * 512);
    Fb[ks] = *(const short8*)(xb + tb + ks * 512);
    Fc[ks] = *(const short8*)(xc + tb + ks * 512);
  }
}

// Selection: keys + depth-4 tree-min; on any improvement run the EXACT full
// INSERT_CAND ladder in ascending r (= ascending j) -- verified semantics.
__device__ __forceinline__ void do_select(const f32x16& acc,
                                          const float* __restrict__ sq, int t,
                                          int h, float (&bd)[KNN],
                                          int (&bj)[KNN]) {
  const int sbase = t * 32 + 4 * h;
  float4 S4[4];
#pragma unroll
  for (int g = 0; g < 4; ++g) S4[g] = *(const float4*)(sq + sbase + 8 * g);
  const float sqa[16] = {S4[0].x, S4[0].y, S4[0].z, S4[0].w,
                         S4[1].x, S4[1].y, S4[1].z, S4[1].w,
                         S4[2].x, S4[2].y, S4[2].z, S4[2].w,
                         S4[3].x, S4[3].y, S4[3].z, S4[3].w};
  float key[16];
#pragma unroll
  for (int r = 0; r < 16; ++r) key[r] = fmaf(-2.f, acc[r], sqa[r]);  // sq_j-2dot
  float m8[8];
#pragma unroll
  for (int r = 0; r < 8; ++r) m8[r] = fminf(key[r], key[r + 8]);
  float m4[4];
#pragma unroll
  for (int r = 0; r < 4; ++r) m4[r] = fminf(m8[r], m8[r + 4]);
  const float m2a = fminf(m4[0], m4[2]), m2b = fminf(m4[1], m4[3]);
  const float m = fminf(m2a, m2b);
  if (__any(m < bd[5])) {
    const int jbase = t * 32 + 4 * h;
#pragma unroll
    for (int r = 0; r < 16; ++r) { INSERT_CAND(bd, bj, key[r], jbase + ROFF(r)); }
  }
}

__device__ __forceinline__ void xmerge(float (&bd)[KNN], int (&bj)[KNN]) {
  float od[KNN];
  int oj[KNN];
#pragma unroll
  for (int k = 0; k < KNN; ++k) {
    od[k] = __shfl_xor(bd[k], 32);
    oj[k] = __shfl_xor(bj[k], 32);
  }
#pragma unroll
  for (int k = 0; k < KNN; ++k) INSERT_TIE(bd, bj, od[k], oj[k]);
}

__global__ __launch_bounds__(512, 4) void knn_bf16_kernel(
    const short* __restrict__ xa, const short* __restrict__ xb,
    const short* __restrict__ xc, const float* __restrict__ sq,
    float* __restrict__ cand_d, unsigned short* __restrict__ cand_js,
    int* __restrict__ knn_idx, int nchunks) {
  __shared__ __align__(16) short sa[2][2][2048];  // [set][half][tile]
  __shared__ __align__(16) short sb[2][2][2048];
  __shared__ __align__(16) short sc[2][2][2048];
  __shared__ float md[4][KNN][32];
  __shared__ int mj[4][KNN][32];
  const int tid = threadIdx.x;
  const int lane = tid & 63;
  const int w = tid >> 6;              // wave 0..7
  const int wq = w & 3;                // B-tile slot within block
  const int hw = w >> 2;               // A-half (0 or 1)
  const int ct = blockIdx.x * 4 + wq;  // B-tile 0..627 (>=625 pad)
  const int jc = blockIdx.y;           // chunk
  const int h = lane >> 5, col = lane & 31;

  // One B-tile (32 centers) resident in VGPRs (pair waves duplicate load).
  short8 Ba[4], Bb[4], Bc[4];
  load_frag(xa, xb, xc, ct, lane, Ba, Bb, Bc);

  float bd[KNN];
  int bj[KNN];
#pragma unroll
  for (int k = 0; k < KNN; ++k) { bd[k] = __builtin_inff(); bj[k] = 0; }

  const int tbeg = jc * TPC;
  int tend = tbeg + TPC;
  if (tend > NTILES) tend = NTILES;
  const int span = tend - tbeg;            // 207..209
  const int len0 = (span + 1) >> 1;        // half0 length (phase driver N0)
  const int len1 = span - len0;
  const int mylen = hw ? len1 : len0;      // wave-uniform
  const int rbeg = tbeg + (hw ? len0 : 0); // wave's A-range start
  const int N0 = len0;

  // Wave stages quarter wq (= ks slice wq) of ITS half's tile.
  const int wo = wq * 512;                 // short offset within tile
  const int la8 = lane * 8;

#define STAGE(set, idx)                                                       \
  do {                                                                        \
    const size_t tb_ = (size_t)(rbeg + (idx)) * 2048 + wo + la8;              \
    gload_lds16(xa + tb_, &sa[set][hw][wo]);                                  \
    gload_lds16(xb + tb_, &sb[set][hw][wo]);                                  \
    gload_lds16(xc + tb_, &sc[set][hw][wo]);                                  \
  } while (0)

// Per-tile chain order identical to verified: aa,ab,ba,ac,ca,bb per ks.
#define COMPUTE_TILE(set, accvar)                                             \
  do {                                                                        \
    accvar = zero16();                                                        \
    _Pragma("unroll")                                                         \
    for (int ks = 0; ks < 4; ++ks) {                                          \
      const int o_ = ks * 512 + la8;                                          \
      const short8 Aa = *(const short8*)(&sa[set][hw][o_]);                   \
      const short8 Ab = *(const short8*)(&sb[set][hw][o_]);                   \
      const short8 Ac = *(const short8*)(&sc[set][hw][o_]);                   \
      accvar = MFMAB(Aa, Ba[ks], accvar);                                     \
      accvar = MFMAB(Aa, Bb[ks], accvar);                                     \
      accvar = MFMAB(Ab, Ba[ks], accvar);                                     \
      accvar = MFMAB(Aa, Bc[ks], accvar);                                     \
      accvar = MFMAB(Ac, Ba[ks], accvar);                                     \
      accvar = MFMAB(Ab, Bb[ks], accvar);                                     \
    }                                                                         \
  } while (0)

  // Prologue (round-18 schedule, guards on mylen; len1 >= 103 so idx 0,1 ok).
  STAGE(0, 0);
  __syncthreads();
  if (1 < mylen) STAGE(1, 1);
  f32x16 acA, acB;
  COMPUTE_TILE(0, acA);
  __syncthreads();

  // Steady state: compute(t) overlaps select(t-1); selects ascending t.
  int i = 1;
  for (; i + 1 < N0; i += 2) {
    if (i + 1 < mylen) STAGE(0, i + 1);
    if (i < mylen) COMPUTE_TILE(1, acB);
    if (i - 1 < mylen) do_select(acA, sq, rbeg + i - 1, h, bd, bj);
    __syncthreads();
    if (i + 2 < mylen) STAGE(1, i + 2);
    if (i + 1 < mylen) COMPUTE_TILE(0, acA);
    if (i < mylen) do_select(acB, sq, rbeg + i, h, bd, bj);
    __syncthreads();
  }
  if (i < N0) {  // N0 even: trailing phase; set1 holds tile i if valid
    if (i < mylen) COMPUTE_TILE(1, acB);
    if (i - 1 < mylen) do_select(acA, sq, rbeg + i - 1, h, bd, bj);
    if (i < mylen) do_select(acB, sq, rbeg + i, h, bd, bj);
  } else {       // N0 odd: only acA (tile N0-1) may be pending
    if (i - 1 < mylen) do_select(acA, sq, rbeg + i - 1, h, bd, bj);
  }
#undef STAGE
#undef COMPUTE_TILE

  // Merge the two row-halves (lane <-> lane^32) lexicographically.
  xmerge(bd, bj);

  // Pair merge: half-1 waves publish, half-0 waves fold (INSERT_TIE is
  // order-independent; same semantics as the chunk merge).
  __syncthreads();
  if (hw == 1 && h == 0) {
#pragma unroll
    for (int k = 0; k < KNN; ++k) {
      md[wq][k][col] = bd[k];
      mj[wq][k][col] = bj[k];
    }
  }
  __syncthreads();
  if (hw == 0 && h == 0) {
#pragma unroll
    for (int k = 0; k < KNN; ++k) {
      const float dv = md[wq][k][col];
      const int jv = mj[wq][k][col];
      INSERT_TIE(bd, bj, dv, jv);
    }
    const int i0 = ct * 32 + col;  // >= 20000 only for pad tiles 625..627
    if (i0 < N_NODES) {
      if (nchunks == 1) {
#pragma unroll
        for (int k = 0; k < KNN; ++k) knn_idx[(size_t)i0 * KNN + k] = bj[k];
      } else {
#pragma unroll
        for (int k = 0; k < KNN; ++k) {
          const size_t off = ((size_t)jc * KNN + k) * N_PAD + i0;
          cand_d[off] = bd[k];
          cand_js[off] = (unsigned short)bj[k];
        }
      }
    }
  }
}

// Merge u16-j chunk candidates (ascending jc = ascending j ranges preserves
// the lowest-j-wins tie discipline; per-chunk lists already sorted asc).
__global__ void knn_merge_u16_kernel(const float* __restrict__ cand_d,
                                     const unsigned short* __restrict__ cand_js,
                                     int* __restrict__ knn_idx, int nchunks) {
  const int i = blockIdx.x * blockDim.x + threadIdx.x;
  if (i >= N_NODES) return;
  float bd[KNN];
  int bj[KNN];
#pragma unroll
  for (int k = 0; k < KNN; ++k) { bd[k] = __builtin_inff(); bj[k] = 0; }
  for (int jc = 0; jc < nchunks; ++jc) {
#pragma unroll
    for (int k = 0; k < KNN; ++k) {
      const size_t off = ((size_t)jc * KNN + k) * N_PAD + i;
      const float d = cand_d[off];
      const int j = (int)cand_js[off];
      INSERT_CAND(bd, bj, d, j);
    }
  }
#pragma unroll
  for (int k = 0; k < KNN; ++k) knn_idx[(size_t)i * KNN + k] = bj[k];
}

// ---------------------------------------------------------------------------
// Fallback VALU path (proven round-4) -- tiny-ws only.
// ---------------------------------------------------------------------------
__global__ void sq_kernel(const float* __restrict__ x, float* __restrict__ sq) {
  const int i = blockIdx.x * blockDim.x + threadIdx.x;
  if (i >= N_NODES) return;
  const float4* r4 = (const float4*)(x + (size_t)i * FDIM);
  float s = 0.f;
#pragma unroll
  for (int q = 0; q < 16; ++q) {
    const float4 a = r4[q];
    s = fmaf(a.x, a.x, s);
    s = fmaf(a.y, a.y, s);
    s = fmaf(a.z, a.z, s);
    s = fmaf(a.w, a.w, s);
  }
  sq[i] = s;
}

__global__ __launch_bounds__(RPB, 2) void knn_partial_kernel(
    const float* __restrict__ x, const float* __restrict__ sq,
    float* __restrict__ cand_d, int* __restrict__ cand_j,
    int* __restrict__ knn_idx, int jchunk, int nchunks) {
  __shared__ __align__(16) float xs[TILE_J][FDIM + 4];
  __shared__ float sqs[TILE_J];
  const int tid = threadIdx.x;
  const int i = blockIdx.x * RPB + tid;
  const bool valid = i < N_NODES;
  const int jc = blockIdx.y;

  float xi[FDIM];
  float sqi = 0.f;
  if (valid) {
    const float4* r4 = (const float4*)(x + (size_t)i * FDIM);
#pragma unroll
    for (int q = 0; q < 16; ++q) {
      const float4 a = r4[q];
      xi[q * 4 + 0] = a.x; xi[q * 4 + 1] = a.y;
      xi[q * 4 + 2] = a.z; xi[q * 4 + 3] = a.w;
    }
    sqi = sq[i];
  } else {
#pragma unroll
    for (int f = 0; f < FDIM; ++f) xi[f] = 0.f;
  }
#pragma unroll
  for (int f = 0; f < FDIM; ++f) asm volatile("" : "+v"(xi[f]));

  float bd[KNN];
  int bj[KNN];
#pragma unroll
  for (int k = 0; k < KNN; ++k) { bd[k] = __builtin_inff(); bj[k] = 0; }

  const int jcbase = jc * jchunk;
  for (int t0 = 0; t0 < jchunk; t0 += TILE_J) {
    const int jt = jcbase + t0;
    __syncthreads();
    {
      const int jj = tid >> 2;
      const int f0 = (tid & 3) * 16;
      const int j = jt + jj;
      float4* dst = (float4*)&xs[jj][f0];
      if (j < N_NODES) {
        const float4* src = (const float4*)(x + (size_t)j * FDIM + f0);
        dst[0] = src[0];
        dst[1] = src[1];
        dst[2] = src[2];
        dst[3] = src[3];
      } else {
        const float4 z = make_float4(0.f, 0.f, 0.f, 0.f);
        dst[0] = z; dst[1] = z; dst[2] = z; dst[3] = z;
      }
      if (tid < TILE_J) {
        const int j2 = jt + tid;
        sqs[tid] = (j2 < N_NODES) ? sq[j2] : 0.f;
      }
    }
    __syncthreads();
    const int rem = N_NODES - jt;
    const int jmax = rem < TILE_J ? rem : TILE_J;
    for (int jj = 0; jj < jmax; ++jj) {
      const float4* xr4 = (const float4*)&xs[jj][0];
      float dot = 0.f;
#pragma unroll
      for (int q = 0; q < 16; ++q) {
        const float4 v = xr4[q];
        dot = fmaf(xi[q * 4 + 0], v.x, dot);
        dot = fmaf(xi[q * 4 + 1], v.y, dot);
        dot = fmaf(xi[q * 4 + 2], v.z, dot);
        dot = fmaf(xi[q * 4 + 3], v.w, dot);
      }
      const float d = fmaf(-2.f, dot, sqi + sqs[jj]);
      const int j = jt + jj;
      INSERT_CAND(bd, bj, d, j);
    }
  }

  if (valid) {
    if (nchunks == 1) {
#pragma unroll
      for (int k = 0; k < KNN; ++k) knn_idx[(size_t)i * KNN + k] = bj[k];
    } else {
#pragma unroll
      for (int k = 0; k < KNN; ++k) {
        const size_t off = ((size_t)jc * KNN + k) * N_PAD + i;
        cand_d[off] = bd[k];
        cand_j[off] = bj[k];
      }
    }
  }
}

__global__ void knn_merge_kernel(const float* __restrict__ cand_d,
                                 const int* __restrict__ cand_j,
                                 int* __restrict__ knn_idx, int nchunks) {
  const int i = blockIdx.x * blockDim.x + threadIdx.x;
  if (i >= N_NODES) return;
  float bd[KNN];
  int bj[KNN];
#pragma unroll
  for (int k = 0; k < KNN; ++k) { bd[k] = __builtin_inff(); bj[k] = 0; }
  for (int jc = 0; jc < nchunks; ++jc) {
#pragma unroll
    for (int k = 0; k < KNN; ++k) {
      const size_t off = ((size_t)jc * KNN + k) * N_PAD + i;
      const float d = cand_d[off];
      const int j = cand_j[off];
      INSERT_CAND(bd, bj, d, j);
    }
  }
#pragma unroll
  for (int k = 0; k < KNN; ++k) knn_idx[(size_t)i * KNN + k] = bj[k];
}

// ---------------------------------------------------------------------------
// MLP: 4 nodes per block -- W1/W2 read once per block (traffic /4).
// Per-node fma order BITWISE identical to the verified single-node mlp
// (ascending f / ascending hh; node loop outside) -- round-20 proved this
// ordering gives absmax 0.0. acc[4][6]=24 regs: no spill at any VGPR pin.
// ---------------------------------------------------------------------------
__global__ __launch_bounds__(HID) void mlp4_kernel(
    const float* __restrict__ x, const int* __restrict__ knn_idx,
    const float* __restrict__ W1, const float* __restrict__ b1,
    const float* __restrict__ W2, const float* __restrict__ b2,
    float* __restrict__ out) {
  __shared__ float xi_s[MLP_NB][FDIM];
  __shared__ float xd_s[MLP_NB][KNN][FDIM];
  __shared__ float h1_s[MLP_NB][KNN][HID];
  __shared__ int nb[MLP_NB][KNN];
  const int nbase = blockIdx.x * MLP_NB;  // 20000 = 5000*4 exactly
  const int t = threadIdx.x;              // output channel

  if (t < MLP_NB * KNN) {  // 24 < 128
    const int n = t / KNN, k = t % KNN;
    const int v = knn_idx[(size_t)(nbase + n) * KNN + k];
    nb[n][k] = ((unsigned)v < (unsigned)N_NODES) ? v : 0;  // clamp
  }
#pragma unroll
  for (int e = t; e < MLP_NB * FDIM; e += HID) {  // 2 iters
    const int n = e >> 6, f = e & 63;
    xi_s[n][f] = x[(size_t)(nbase + n) * FDIM + f];
  }
  __syncthreads();
  for (int e = t; e < MLP_NB * KNN * FDIM; e += HID) {  // 12 iters
    const int n = e / (KNN * FDIM);
    const int rem = e - n * (KNN * FDIM);
    const int k = rem >> 6, f = rem & 63;
    xd_s[n][k][f] = x[(size_t)nb[n][k] * FDIM + f] - xi_s[n][f];
  }
  __syncthreads();

  // Layer 1: s0[n] = b1 + sum_f xi*W1 (ascending f, same chain per node).
  float s0[MLP_NB];
#pragma unroll
  for (int n = 0; n < MLP_NB; ++n) s0[n] = b1[t];
  for (int f = 0; f < FDIM; ++f) {
    const float wv = W1[f * HID + t];
#pragma unroll
    for (int n = 0; n < MLP_NB; ++n) s0[n] = fmaf(xi_s[n][f], wv, s0[n]);
  }
  float acc[MLP_NB][KNN];
#pragma unroll
  for (int n = 0; n < MLP_NB; ++n)
#pragma unroll
    for (int k = 0; k < KNN; ++k) acc[n][k] = s0[n];
  for (int f = 0; f < FDIM; ++f) {
    const float wv = W1[(FDIM + f) * HID + t];
#pragma unroll
    for (int n = 0; n < MLP_NB; ++n)
#pragma unroll
      for (int k = 0; k < KNN; ++k)
        acc[n][k] = fmaf(xd_s[n][k][f], wv, acc[n][k]);
  }
#pragma unroll
  for (int n = 0; n < MLP_NB; ++n)
#pragma unroll
    for (int k = 0; k < KNN; ++k) h1_s[n][k][t] = fmaxf(acc[n][k], 0.f);
  __syncthreads();

  // Layer 2 (no relu) + max aggregation (ascending hh, same chain per node).
  float acc2[MLP_NB][KNN];
  const float bb = b2[t];
#pragma unroll
  for (int n = 0; n < MLP_NB; ++n)
#pragma unroll
    for (int k = 0; k < KNN; ++k) acc2[n][k] = bb;
  for (int hh = 0; hh < HID; ++hh) {
    const float wv = W2[hh * HID + t];
#pragma unroll
    for (int n = 0; n < MLP_NB; ++n)
#pragma unroll
      for (int k = 0; k < KNN; ++k)
        acc2[n][k] = fmaf(h1_s[n][k][hh], wv, acc2[n][k]);
  }
#pragma unroll
  for (int n = 0; n < MLP_NB; ++n) {
    float m = acc2[n][0];
#pragma unroll
    for (int k = 1; k < KNN; ++k) m = fmaxf(m, acc2[n][k]);
    out[(size_t)(nbase + n) * HID + t] = m;
  }
}

extern "C" void kernel_launch(void* const* d_in, const int* in_sizes, int n_in,
                              void* d_out, int out_size, void* d_ws, size_t ws_size,
                              hipStream_t stream) {
  const float* x  = (const float*)d_in[0];
  const float* W1 = (const float*)d_in[2];
  const float* b1 = (const float*)d_in[3];
  const float* W2 = (const float*)d_in[4];
  const float* b2 = (const float*)d_in[5];
  float* out = (float*)d_out;
  char* ws = (char*)d_ws;
  const size_t PER_CHUNK = (size_t)KNN * N_PAD * 8;  // 983,040 B (fallback)

  if (ws_size >= 0x998000) {
    // MFMA layout (10,059,776 B required; inferred ws >= 10,420,224):
    //   0x000000 sq      (20096 f32 used; 0x20000 reserved)
    //   0x020000 xa      (628*2048 s16 = 2,572,288 B) -> 0x294000
    //   0x294000 xb      -> 0x508000
    //   0x508000 xc      -> 0x77C000
    //   0x77C000 cand_d  (3*6*20480 f32 = 1,474,560 B) -> 0x8E4000
    //   0x8E4000 cand_js (3*6*20480 u16 = 737,280 B)  -> 0x998000
    //   knn aliases xa at 0x20000 (xa dead after the scan).
    float* sq   = (float*)ws;
    short* xa   = (short*)(ws + 0x20000);
    short* xb   = (short*)(ws + 0x294000);
    short* xc   = (short*)(ws + 0x508000);
    float* cand_d = (float*)(ws + 0x77C000);
    unsigned short* cand_js = (unsigned short*)(ws + 0x8E4000);
    int* knn = (int*)(ws + 0x20000);

    prep_kernel<<<dim3((PREP_TILES * 32 + 255) / 256), dim3(256), 0, stream>>>(
        x, xa, xb, xc, sq);
    knn_bf16_kernel<<<dim3(NBLK, NCHUNK), dim3(512), 0, stream>>>(
        xa, xb, xc, sq, cand_d, cand_js, knn, NCHUNK);
    knn_merge_u16_kernel<<<dim3((N_NODES + 255) / 256), dim3(256), 0, stream>>>(
        cand_d, cand_js, knn, NCHUNK);
    mlp4_kernel<<<dim3(N_NODES / MLP_NB), dim3(HID), 0, stream>>>(
        x, knn, W1, b1, W2, b2, out);
  } else {
    // Fallback: round-4 layout (sq | knn | cand at 0x90000)
    float* sq = (float*)ws;
    int* knn  = (int*)(ws + (size_t)N_PAD * 4);
    const size_t BASE = 0x90000;
    int nc = 1;
    if (ws_size > BASE + PER_CHUNK) {
      size_t fit = (ws_size - BASE) / PER_CHUNK;
      nc = fit < (size_t)MAX_CHUNKS ? (int)fit : MAX_CHUNKS;
      if (nc < 1) nc = 1;
    }
    int jchunk = ((N_NODES + nc - 1) / nc + TILE_J - 1) / TILE_J * TILE_J;
    float* cand_d = (float*)(ws + BASE);
    int* cand_j = (int*)(ws + BASE + (size_t)nc * KNN * N_PAD * 4);

    sq_kernel<<<dim3((N_NODES + 255) / 256), dim3(256), 0, stream>>>(x, sq);
    knn_partial_kernel<<<dim3((N_NODES + RPB - 1) / RPB, nc), dim3(RPB), 0, stream>>>(
        x, sq, cand_d, cand_j, knn, jchunk, nc);
    if (nc > 1) {
      knn_merge_kernel<<<dim3((N_NODES + 255) / 256), dim3(256), 0, stream>>>(
          cand_d, cand_j, knn, nc);
    }
    mlp4_kernel<<<dim3(N_NODES / MLP_NB), dim3(HID), 0, stream>>>(
        x, knn, W1, b1, W2, b2, out);
  }
}

// Round 19
// 531.438 us; speedup vs baseline: 1.1863x; 1.1030x over previous
//
#include <hip/hip_runtime.h>

// EdgeCNN (DynamicEdgeConv): N=20000, F=64, H=128, K=6 (incl self). All f32.
// ROUND-23: revert mlp to 1-node (A/B proved: mlp1 554.6 < mlp4 586 < mlp8
// 630 -- weight re-reads were L2-broadcast, never the cost), and raise knn
// occupancy by ALIASING the pair-merge scratch onto the dead staging LDS:
// md/mj (6144B) are only touched after the scan loop, when sa/sb are dead
// (all reads + async stages drained by the loop's own barriers; merge
// section opens with another barrier). LDS 55296 -> 49152B = 3 blocks/CU
// (147.5KB <= 160KB): 24 waves/CU, 6/SIMD -- +50% TLP for the 2-phase
// skeleton. Everything else BYTE-IDENTICAL to the round-19 verified scan.

#define N_NODES 20000
#define FDIM 64
#define KNN 6
#define HID 128
#define N_PAD 20480
#define NTILES 625      // A-tiles: 20000/32 exactly
#define PREP_TILES 628  // B-side pad: 157 blocks x 4 B-tiles = 628 tiles
#define NBLK 157        // blocks per chunk (4 B-tiles, 8 waves each)
#define NCHUNK 3
#define TPC 209         // ceil(625/3); chunks cover 209/209/207 tiles
#define RPB 256
#define TILE_J 64
#define MAX_CHUNKS 10

typedef __attribute__((ext_vector_type(8))) short short8;
typedef __attribute__((ext_vector_type(16))) float f32x16;

#define MFMAB(A, B, C) __builtin_amdgcn_mfma_f32_32x32x16_bf16((A), (B), (C), 0, 0, 0)
#define ROFF(r) (((r) & 3) + 8 * ((r) >> 2))

// Sorted-ascending 6-slot insert; strict '<' => earlier (lower-j) candidate
// wins ties when scanned in ascending j, matching jax.lax.top_k stability.
#define INSERT_CAND(bd, bj, dv, jv) do {                                      \
  if ((dv) < bd[5]) {                                                         \
    const bool c0 = (dv) < bd[0], c1 = (dv) < bd[1], c2 = (dv) < bd[2];       \
    const bool c3 = (dv) < bd[3], c4 = (dv) < bd[4];                          \
    bd[5] = c4 ? bd[4] : (dv);              bj[5] = c4 ? bj[4] : (jv);        \
    bd[4] = c4 ? (c3 ? bd[3] : (dv)) : bd[4]; bj[4] = c4 ? (c3 ? bj[3] : (jv)) : bj[4]; \
    bd[3] = c3 ? (c2 ? bd[2] : (dv)) : bd[3]; bj[3] = c3 ? (c2 ? bj[2] : (jv)) : bj[3]; \
    bd[2] = c2 ? (c1 ? bd[1] : (dv)) : bd[2]; bj[2] = c2 ? (c1 ? bj[1] : (jv)) : bj[2]; \
    bd[1] = c1 ? (c0 ? bd[0] : (dv)) : bd[1]; bj[1] = c1 ? (c0 ? bj[0] : (jv)) : bj[1]; \
    bd[0] = c0 ? (dv) : bd[0];              bj[0] = c0 ? (jv) : bj[0];        \
  }                                                                           \
} while (0)

#define LEXLT(dv, jv, ds, js) (((dv) < (ds)) || ((dv) == (ds) && (jv) < (js)))
#define INSERT_TIE(bd, bj, dv, jv) do {                                       \
  if (LEXLT((dv), (jv), bd[5], bj[5])) {                                      \
    const bool c0 = LEXLT((dv), (jv), bd[0], bj[0]);                          \
    const bool c1 = LEXLT((dv), (jv), bd[1], bj[1]);                          \
    const bool c2 = LEXLT((dv), (jv), bd[2], bj[2]);                          \
    const bool c3 = LEXLT((dv), (jv), bd[3], bj[3]);                          \
    const bool c4 = LEXLT((dv), (jv), bd[4], bj[4]);                          \
    bd[5] = c4 ? bd[4] : (dv);              bj[5] = c4 ? bj[4] : (jv);        \
    bd[4] = c4 ? (c3 ? bd[3] : (dv)) : bd[4]; bj[4] = c4 ? (c3 ? bj[3] : (jv)) : bj[4]; \
    bd[3] = c3 ? (c2 ? bd[2] : (dv)) : bd[3]; bj[3] = c3 ? (c2 ? bj[2] : (jv)) : bj[3]; \
    bd[2] = c2 ? (c1 ? bd[1] : (dv)) : bd[2]; bj[2] = c2 ? (c1 ? bj[1] : (jv)) : bj[2]; \
    bd[1] = c1 ? (c0 ? bd[0] : (dv)) : bd[1]; bj[1] = c1 ? (c0 ? bj[0] : (jv)) : bj[1]; \
    bd[0] = c0 ? (dv) : bd[0];              bj[0] = c0 ? (jv) : bj[0];        \
  }                                                                           \
} while (0)

__device__ __forceinline__ f32x16 zero16() {
  f32x16 v;
#pragma unroll
  for (int i = 0; i < 16; ++i) v[i] = 0.f;
  return v;
}

__device__ __forceinline__ unsigned short bf16_rne(float x) {
  unsigned u = __float_as_uint(x);
  u += 0x7fffu + ((u >> 16) & 1u);
  return (unsigned short)(u >> 16);
}
__device__ __forceinline__ float bf16_tof(unsigned short h) {
  return __uint_as_float(((unsigned)h) << 16);
}

// Async global->LDS, 16B per lane: LDS dest = wave-uniform base + lane*16,
// global src per-lane (guide section 5 / m97 pattern).
__device__ __forceinline__ void gload_lds16(const void* g, void* l) {
  __builtin_amdgcn_global_load_lds(
      (const __attribute__((address_space(1))) void*)g,
      (__attribute__((address_space(3))) void*)l, 16, 0, 0);
}

// ---------------------------------------------------------------------------
// Prep: sq + exact 3-term bf16 split (x = a+b+c), fragment-major layout:
// element (tile, ks, lane=(khalf<<5)|row, j) at tile*2048 + ks*512 + lane*8+j
// with feature = ks*16 + khalf*8 + j. Tiles 625..627 zeroed (B-side pad).
// ---------------------------------------------------------------------------
__global__ void prep_kernel(const float* __restrict__ x, short* __restrict__ xa,
                            short* __restrict__ xb, short* __restrict__ xc,
                            float* __restrict__ sq) {
  const int n = blockIdx.x * blockDim.x + threadIdx.x;
  if (n >= PREP_TILES * 32) return;
  const int tile = n >> 5, row = n & 31;
  unsigned short a[FDIM], b[FDIM], c[FDIM];
  float s = 0.f;
  if (n < N_NODES) {
    const float4* r4 = (const float4*)(x + (size_t)n * FDIM);
#pragma unroll
    for (int q = 0; q < 16; ++q) {
      const float4 v = r4[q];
      const float vv[4] = {v.x, v.y, v.z, v.w};
#pragma unroll
      for (int e = 0; e < 4; ++e) {
        const float xv = vv[e];
        s = fmaf(xv, xv, s);
        const unsigned short ua = bf16_rne(xv);
        const float r1 = xv - bf16_tof(ua);      // exact
        const unsigned short ub = bf16_rne(r1);
        const float r2 = r1 - bf16_tof(ub);      // exact
        a[q * 4 + e] = ua; b[q * 4 + e] = ub; c[q * 4 + e] = bf16_rne(r2);
      }
    }
  } else {
#pragma unroll
    for (int f = 0; f < FDIM; ++f) { a[f] = 0; b[f] = 0; c[f] = 0; }
    s = __builtin_inff();
  }
  sq[n] = s;
#pragma unroll
  for (int ks = 0; ks < 4; ++ks) {
#pragma unroll
    for (int hh = 0; hh < 2; ++hh) {
      short8 va, vb, vc;
#pragma unroll
      for (int j = 0; j < 8; ++j) {
        const int f = ks * 16 + hh * 8 + j;
        va[j] = (short)a[f]; vb[j] = (short)b[f]; vc[j] = (short)c[f];
      }
      const size_t off = (size_t)tile * 2048 + ks * 512 + (size_t)((hh << 5) | row) * 8;
      *(short8*)(xa + off) = va;
      *(short8*)(xb + off) = vb;
      *(short8*)(xc + off) = vc;
    }
  }
}

// ---------------------------------------------------------------------------
// bf16 MFMA kNN scan (schedule BYTE-IDENTICAL to verified round-19): 8-wave
// blocks; wave pair (wq, wq+4) shares B-tile, splits A-range in half. The
// pair-merge scratch ALIASES the dead staging LDS (saves 6KB -> 3 blk/CU).
// ---------------------------------------------------------------------------
__device__ __forceinline__ void load_frag(const short* __restrict__ xa,
                                          const short* __restrict__ xb,
                                          const short* __restrict__ xc, int t,
                                          int lane, short8 (&Fa)[4],
                                          short8 (&Fb)[4], short8 (&Fc)[4]) {
  const size_t tb = (size_t)t * 2048 + (size_t)lane * 8;
#pragma unroll
  for (int ks = 0; ks < 4; ++ks) {
    Fa[ks] = *(const short8*)(xa + tb + ks * 512);
    Fb[ks] = *(const short8*)(xb + tb + ks * 512);
    Fc[ks] = *(const short8*)(xc + tb + ks * 512);
  }
}

// Selection: keys + depth-4 tree-min; on any improvement run the EXACT full
// INSERT_CAND ladder in ascending r (= ascending j) -- verified semantics.
__device__ __forceinline__ void do_select(const f32x16& acc,
                                          const float* __restrict__ sq, int t,
                                          int h, float (&bd)[KNN],
                                          int (&bj)[KNN]) {
  const int sbase = t * 32 + 4 * h;
  float4 S4[4];
#pragma unroll
  for (int g = 0; g < 4; ++g) S4[g] = *(const float4*)(sq + sbase + 8 * g);
  const float sqa[16] = {S4[0].x, S4[0].y, S4[0].z, S4[0].w,
                         S4[1].x, S4[1].y, S4[1].z, S4[1].w,
                         S4[2].x, S4[2].y, S4[2].z, S4[2].w,
                         S4[3].x, S4[3].y, S4[3].z, S4[3].w};
  float key[16];
#pragma unroll
  for (int r = 0; r < 16; ++r) key[r] = fmaf(-2.f, acc[r], sqa[r]);  // sq_j-2dot
  float m8[8];
#pragma unroll
  for (int r = 0; r < 8; ++r) m8[r] = fminf(key[r], key[r + 8]);
  float m4[4];
#pragma unroll
  for (int r = 0; r < 4; ++r) m4[r] = fminf(m8[r], m8[r + 4]);
  const float m2a = fminf(m4[0], m4[2]), m2b = fminf(m4[1], m4[3]);
  const float m = fminf(m2a, m2b);
  if (__any(m < bd[5])) {
    const int jbase = t * 32 + 4 * h;
#pragma unroll
    for (int r = 0; r < 16; ++r) { INSERT_CAND(bd, bj, key[r], jbase + ROFF(r)); }
  }
}

__device__ __forceinline__ void xmerge(float (&bd)[KNN], int (&bj)[KNN]) {
  float od[KNN];
  int oj[KNN];
#pragma unroll
  for (int k = 0; k < KNN; ++k) {
    od[k] = __shfl_xor(bd[k], 32);
    oj[k] = __shfl_xor(bj[k], 32);
  }
#pragma unroll
  for (int k = 0; k < KNN; ++k) INSERT_TIE(bd, bj, od[k], oj[k]);
}

__global__ __launch_bounds__(512, 4) void knn_bf16_kernel(
    const short* __restrict__ xa, const short* __restrict__ xb,
    const short* __restrict__ xc, const float* __restrict__ sq,
    float* __restrict__ cand_d, unsigned short* __restrict__ cand_js,
    int* __restrict__ knn_idx, int nchunks) {
  __shared__ __align__(16) short sa[2][2][2048];  // [set][half][tile]
  __shared__ __align__(16) short sb[2][2][2048];
  __shared__ __align__(16) short sc[2][2][2048];
  // Pair-merge scratch ALIASES sa/sb: only touched after the scan loop, when
  // staging LDS is dead (all sa/sb reads + async stages drained by the
  // loop's barriers; merge section opens with its own barrier). 3072B each.
  float* md = (float*)&sa[0][0][0];  // md[(wq*KNN+k)*32 + col]
  int*   mj = (int*)&sb[0][0][0];
  const int tid = threadIdx.x;
  const int lane = tid & 63;
  const int w = tid >> 6;              // wave 0..7
  const int wq = w & 3;                // B-tile slot within block
  const int hw = w >> 2;               // A-half (0 or 1)
  const int ct = blockIdx.x * 4 + wq;  // B-tile 0..627 (>=625 pad)
  const int jc = blockIdx.y;           // chunk
  const int h = lane >> 5, col = lane & 31;

  // One B-tile (32 centers) resident in VGPRs (pair waves duplicate load).
  short8 Ba[4], Bb[4], Bc[4];
  load_frag(xa, xb, xc, ct, lane, Ba, Bb, Bc);

  float bd[KNN];
  int bj[KNN];
#pragma unroll
  for (int k = 0; k < KNN; ++k) { bd[k] = __builtin_inff(); bj[k] = 0; }

  const int tbeg = jc * TPC;
  int tend = tbeg + TPC;
  if (tend > NTILES) tend = NTILES;
  const int span = tend - tbeg;            // 207..209
  const int len0 = (span + 1) >> 1;        // half0 length (phase driver N0)
  const int len1 = span - len0;
  const int mylen = hw ? len1 : len0;      // wave-uniform
  const int rbeg = tbeg + (hw ? len0 : 0); // wave's A-range start
  const int N0 = len0;

  // Wave stages quarter wq (= ks slice wq) of ITS half's tile.
  const int wo = wq * 512;                 // short offset within tile
  const int la8 = lane * 8;

#define STAGE(set, idx)                                                       \
  do {                                                                        \
    const size_t tb_ = (size_t)(rbeg + (idx)) * 2048 + wo + la8;              \
    gload_lds16(xa + tb_, &sa[set][hw][wo]);                                  \
    gload_lds16(xb + tb_, &sb[set][hw][wo]);                                  \
    gload_lds16(xc + tb_, &sc[set][hw][wo]);                                  \
  } while (0)

// Per-tile chain order identical to verified: aa,ab,ba,ac,ca,bb per ks.
#define COMPUTE_TILE(set, accvar)                                             \
  do {                                                                        \
    accvar = zero16();                                                        \
    _Pragma("unroll")                                                         \
    for (int ks = 0; ks < 4; ++ks) {                                          \
      const int o_ = ks * 512 + la8;                                          \
      const short8 Aa = *(const short8*)(&sa[set][hw][o_]);                   \
      const short8 Ab = *(const short8*)(&sb[set][hw][o_]);                   \
      const short8 Ac = *(const short8*)(&sc[set][hw][o_]);                   \
      accvar = MFMAB(Aa, Ba[ks], accvar);                                     \
      accvar = MFMAB(Aa, Bb[ks], accvar);                                     \
      accvar = MFMAB(Ab, Ba[ks], accvar);                                     \
      accvar = MFMAB(Aa, Bc[ks], accvar);                                     \
      accvar = MFMAB(Ac, Ba[ks], accvar);                                     \
      accvar = MFMAB(Ab, Bb[ks], accvar);                                     \
    }                                                                         \
  } while (0)

  // Prologue (round-18 schedule, guards on mylen; len1 >= 103 so idx 0,1 ok).
  STAGE(0, 0);
  __syncthreads();
  if (1 < mylen) STAGE(1, 1);
  f32x16 acA, acB;
  COMPUTE_TILE(0, acA);
  __syncthreads();

  // Steady state: compute(t) overlaps select(t-1); selects ascending t.
  int i = 1;
  for (; i + 1 < N0; i += 2) {
    if (i + 1 < mylen) STAGE(0, i + 1);
    if (i < mylen) COMPUTE_TILE(1, acB);
    if (i - 1 < mylen) do_select(acA, sq, rbeg + i - 1, h, bd, bj);
    __syncthreads();
    if (i + 2 < mylen) STAGE(1, i + 2);
    if (i + 1 < mylen) COMPUTE_TILE(0, acA);
    if (i < mylen) do_select(acB, sq, rbeg + i, h, bd, bj);
    __syncthreads();
  }
  if (i < N0) {  // N0 even: trailing phase; set1 holds tile i if valid
    if (i < mylen) COMPUTE_TILE(1, acB);
    if (i - 1 < mylen) do_select(acA, sq, rbeg + i - 1, h, bd, bj);
    if (i < mylen) do_select(acB, sq, rbeg + i, h, bd, bj);
  } else {       // N0 odd: only acA (tile N0-1) may be pending
    if (i - 1 < mylen) do_select(acA, sq, rbeg + i - 1, h, bd, bj);
  }
#undef STAGE
#undef COMPUTE_TILE

  // Merge the two row-halves (lane <-> lane^32) lexicographically.
  xmerge(bd, bj);

  // Pair merge: half-1 waves publish, half-0 waves fold (INSERT_TIE is
  // order-independent; same semantics as the chunk merge). md/mj alias the
  // now-dead staging buffers; barriers separate all uses.
  __syncthreads();
  if (hw == 1 && h == 0) {
#pragma unroll
    for (int k = 0; k < KNN; ++k) {
      md[(wq * KNN + k) * 32 + col] = bd[k];
      mj[(wq * KNN + k) * 32 + col] = bj[k];
    }
  }
  __syncthreads();
  if (hw == 0 && h == 0) {
#pragma unroll
    for (int k = 0; k < KNN; ++k) {
      const float dv = md[(wq * KNN + k) * 32 + col];
      const int jv = mj[(wq * KNN + k) * 32 + col];
      INSERT_TIE(bd, bj, dv, jv);
    }
    const int i0 = ct * 32 + col;  // >= 20000 only for pad tiles 625..627
    if (i0 < N_NODES) {
      if (nchunks == 1) {
#pragma unroll
        for (int k = 0; k < KNN; ++k) knn_idx[(size_t)i0 * KNN + k] = bj[k];
      } else {
#pragma unroll
        for (int k = 0; k < KNN; ++k) {
          const size_t off = ((size_t)jc * KNN + k) * N_PAD + i0;
          cand_d[off] = bd[k];
          cand_js[off] = (unsigned short)bj[k];
        }
      }
    }
  }
}

// Merge u16-j chunk candidates (ascending jc = ascending j ranges preserves
// the lowest-j-wins tie discipline; per-chunk lists already sorted asc).
__global__ void knn_merge_u16_kernel(const float* __restrict__ cand_d,
                                     const unsigned short* __restrict__ cand_js,
                                     int* __restrict__ knn_idx, int nchunks) {
  const int i = blockIdx.x * blockDim.x + threadIdx.x;
  if (i >= N_NODES) return;
  float bd[KNN];
  int bj[KNN];
#pragma unroll
  for (int k = 0; k < KNN; ++k) { bd[k] = __builtin_inff(); bj[k] = 0; }
  for (int jc = 0; jc < nchunks; ++jc) {
#pragma unroll
    for (int k = 0; k < KNN; ++k) {
      const size_t off = ((size_t)jc * KNN + k) * N_PAD + i;
      const float d = cand_d[off];
      const int j = (int)cand_js[off];
      INSERT_CAND(bd, bj, d, j);
    }
  }
#pragma unroll
  for (int k = 0; k < KNN; ++k) knn_idx[(size_t)i * KNN + k] = bj[k];
}

// ---------------------------------------------------------------------------
// Fallback VALU path (proven round-4) -- tiny-ws only.
// ---------------------------------------------------------------------------
__global__ void sq_kernel(const float* __restrict__ x, float* __restrict__ sq) {
  const int i = blockIdx.x * blockDim.x + threadIdx.x;
  if (i >= N_NODES) return;
  const float4* r4 = (const float4*)(x + (size_t)i * FDIM);
  float s = 0.f;
#pragma unroll
  for (int q = 0; q < 16; ++q) {
    const float4 a = r4[q];
    s = fmaf(a.x, a.x, s);
    s = fmaf(a.y, a.y, s);
    s = fmaf(a.z, a.z, s);
    s = fmaf(a.w, a.w, s);
  }
  sq[i] = s;
}

__global__ __launch_bounds__(RPB, 2) void knn_partial_kernel(
    const float* __restrict__ x, const float* __restrict__ sq,
    float* __restrict__ cand_d, int* __restrict__ cand_j,
    int* __restrict__ knn_idx, int jchunk, int nchunks) {
  __shared__ __align__(16) float xs[TILE_J][FDIM + 4];
  __shared__ float sqs[TILE_J];
  const int tid = threadIdx.x;
  const int i = blockIdx.x * RPB + tid;
  const bool valid = i < N_NODES;
  const int jc = blockIdx.y;

  float xi[FDIM];
  float sqi = 0.f;
  if (valid) {
    const float4* r4 = (const float4*)(x + (size_t)i * FDIM);
#pragma unroll
    for (int q = 0; q < 16; ++q) {
      const float4 a = r4[q];
      xi[q * 4 + 0] = a.x; xi[q * 4 + 1] = a.y;
      xi[q * 4 + 2] = a.z; xi[q * 4 + 3] = a.w;
    }
    sqi = sq[i];
  } else {
#pragma unroll
    for (int f = 0; f < FDIM; ++f) xi[f] = 0.f;
  }
#pragma unroll
  for (int f = 0; f < FDIM; ++f) asm volatile("" : "+v"(xi[f]));

  float bd[KNN];
  int bj[KNN];
#pragma unroll
  for (int k = 0; k < KNN; ++k) { bd[k] = __builtin_inff(); bj[k] = 0; }

  const int jcbase = jc * jchunk;
  for (int t0 = 0; t0 < jchunk; t0 += TILE_J) {
    const int jt = jcbase + t0;
    __syncthreads();
    {
      const int jj = tid >> 2;
      const int f0 = (tid & 3) * 16;
      const int j = jt + jj;
      float4* dst = (float4*)&xs[jj][f0];
      if (j < N_NODES) {
        const float4* src = (const float4*)(x + (size_t)j * FDIM + f0);
        dst[0] = src[0];
        dst[1] = src[1];
        dst[2] = src[2];
        dst[3] = src[3];
      } else {
        const float4 z = make_float4(0.f, 0.f, 0.f, 0.f);
        dst[0] = z; dst[1] = z; dst[2] = z; dst[3] = z;
      }
      if (tid < TILE_J) {
        const int j2 = jt + tid;
        sqs[tid] = (j2 < N_NODES) ? sq[j2] : 0.f;
      }
    }
    __syncthreads();
    const int rem = N_NODES - jt;
    const int jmax = rem < TILE_J ? rem : TILE_J;
    for (int jj = 0; jj < jmax; ++jj) {
      const float4* xr4 = (const float4*)&xs[jj][0];
      float dot = 0.f;
#pragma unroll
      for (int q = 0; q < 16; ++q) {
        const float4 v = xr4[q];
        dot = fmaf(xi[q * 4 + 0], v.x, dot);
        dot = fmaf(xi[q * 4 + 1], v.y, dot);
        dot = fmaf(xi[q * 4 + 2], v.z, dot);
        dot = fmaf(xi[q * 4 + 3], v.w, dot);
      }
      const float d = fmaf(-2.f, dot, sqi + sqs[jj]);
      const int j = jt + jj;
      INSERT_CAND(bd, bj, d, j);
    }
  }

  if (valid) {
    if (nchunks == 1) {
#pragma unroll
      for (int k = 0; k < KNN; ++k) knn_idx[(size_t)i * KNN + k] = bj[k];
    } else {
#pragma unroll
      for (int k = 0; k < KNN; ++k) {
        const size_t off = ((size_t)jc * KNN + k) * N_PAD + i;
        cand_d[off] = bd[k];
        cand_j[off] = bj[k];
      }
    }
  }
}

__global__ void knn_merge_kernel(const float* __restrict__ cand_d,
                                 const int* __restrict__ cand_j,
                                 int* __restrict__ knn_idx, int nchunks) {
  const int i = blockIdx.x * blockDim.x + threadIdx.x;
  if (i >= N_NODES) return;
  float bd[KNN];
  int bj[KNN];
#pragma unroll
  for (int k = 0; k < KNN; ++k) { bd[k] = __builtin_inff(); bj[k] = 0; }
  for (int jc = 0; jc < nchunks; ++jc) {
#pragma unroll
    for (int k = 0; k < KNN; ++k) {
      const size_t off = ((size_t)jc * KNN + k) * N_PAD + i;
      const float d = cand_d[off];
      const int j = cand_j[off];
      INSERT_CAND(bd, bj, d, j);
    }
  }
#pragma unroll
  for (int k = 0; k < KNN; ++k) knn_idx[(size_t)i * KNN + k] = bj[k];
}

// ---------------------------------------------------------------------------
// MLP (verified single-node version -- A/B best).
// ---------------------------------------------------------------------------
__global__ __launch_bounds__(HID) void mlp_kernel(
    const float* __restrict__ x, const int* __restrict__ knn_idx,
    const float* __restrict__ W1, const float* __restrict__ b1,
    const float* __restrict__ W2, const float* __restrict__ b2,
    float* __restrict__ out) {
  __shared__ float xi_s[FDIM];
  __shared__ float xd_s[KNN][FDIM];
  __shared__ float h1_s[KNN][HID];
  __shared__ int nb[KNN];
  const int i = blockIdx.x;
  const int t = threadIdx.x;
  if (t < KNN) {
    const int v = knn_idx[(size_t)i * KNN + t];
    nb[t] = ((unsigned)v < (unsigned)N_NODES) ? v : 0;  // clamp: cannot fault
  }
  if (t < FDIM) xi_s[t] = x[(size_t)i * FDIM + t];
  __syncthreads();
  for (int e = t; e < KNN * FDIM; e += HID) {
    const int k = e >> 6;
    const int f = e & 63;
    xd_s[k][f] = x[(size_t)nb[k] * FDIM + f] - xi_s[f];
  }
  __syncthreads();

  float s0 = b1[t];
  for (int f = 0; f < FDIM; ++f) {
    const float w = W1[f * HID + t];
    s0 = fmaf(xi_s[f], w, s0);
  }
  float acc[KNN];
#pragma unroll
  for (int k = 0; k < KNN; ++k) acc[k] = s0;
  for (int f = 0; f < FDIM; ++f) {
    const float w = W1[(FDIM + f) * HID + t];
#pragma unroll
    for (int k = 0; k < KNN; ++k) acc[k] = fmaf(xd_s[k][f], w, acc[k]);
  }
#pragma unroll
  for (int k = 0; k < KNN; ++k) h1_s[k][t] = fmaxf(acc[k], 0.f);
  __syncthreads();

  float acc2[KNN];
  const float bb = b2[t];
#pragma unroll
  for (int k = 0; k < KNN; ++k) acc2[k] = bb;
  for (int hh = 0; hh < HID; ++hh) {
    const float w = W2[hh * HID + t];
#pragma unroll
    for (int k = 0; k < KNN; ++k) acc2[k] = fmaf(h1_s[k][hh], w, acc2[k]);
  }
  float m = acc2[0];
#pragma unroll
  for (int k = 1; k < KNN; ++k) m = fmaxf(m, acc2[k]);
  out[(size_t)i * HID + t] = m;
}

extern "C" void kernel_launch(void* const* d_in, const int* in_sizes, int n_in,
                              void* d_out, int out_size, void* d_ws, size_t ws_size,
                              hipStream_t stream) {
  const float* x  = (const float*)d_in[0];
  const float* W1 = (const float*)d_in[2];
  const float* b1 = (const float*)d_in[3];
  const float* W2 = (const float*)d_in[4];
  const float* b2 = (const float*)d_in[5];
  float* out = (float*)d_out;
  char* ws = (char*)d_ws;
  const size_t PER_CHUNK = (size_t)KNN * N_PAD * 8;  // 983,040 B (fallback)

  if (ws_size >= 0x998000) {
    // MFMA layout (10,059,776 B required; inferred ws >= 10,420,224):
    //   0x000000 sq      (20096 f32 used; 0x20000 reserved)
    //   0x020000 xa      (628*2048 s16 = 2,572,288 B) -> 0x294000
    //   0x294000 xb      -> 0x508000
    //   0x508000 xc      -> 0x77C000
    //   0x77C000 cand_d  (3*6*20480 f32 = 1,474,560 B) -> 0x8E4000
    //   0x8E4000 cand_js (3*6*20480 u16 = 737,280 B)  -> 0x998000
    //   knn aliases xa at 0x20000 (xa dead after the scan).
    float* sq   = (float*)ws;
    short* xa   = (short*)(ws + 0x20000);
    short* xb   = (short*)(ws + 0x294000);
    short* xc   = (short*)(ws + 0x508000);
    float* cand_d = (float*)(ws + 0x77C000);
    unsigned short* cand_js = (unsigned short*)(ws + 0x8E4000);
    int* knn = (int*)(ws + 0x20000);

    prep_kernel<<<dim3((PREP_TILES * 32 + 255) / 256), dim3(256), 0, stream>>>(
        x, xa, xb, xc, sq);
    knn_bf16_kernel<<<dim3(NBLK, NCHUNK), dim3(512), 0, stream>>>(
        xa, xb, xc, sq, cand_d, cand_js, knn, NCHUNK);
    knn_merge_u16_kernel<<<dim3((N_NODES + 255) / 256), dim3(256), 0, stream>>>(
        cand_d, cand_js, knn, NCHUNK);
    mlp_kernel<<<dim3(N_NODES), dim3(HID), 0, stream>>>(x, knn, W1, b1, W2, b2, out);
  } else {
    // Fallback: round-4 layout (sq | knn | cand at 0x90000)
    float* sq = (float*)ws;
    int* knn  = (int*)(ws + (size_t)N_PAD * 4);
    const size_t BASE = 0x90000;
    int nc = 1;
    if (ws_size > BASE + PER_CHUNK) {
      size_t fit = (ws_size - BASE) / PER_CHUNK;
      nc = fit < (size_t)MAX_CHUNKS ? (int)fit : MAX_CHUNKS;
      if (nc < 1) nc = 1;
    }
    int jchunk = ((N_NODES + nc - 1) / nc + TILE_J - 1) / TILE_J * TILE_J;
    float* cand_d = (float*)(ws + BASE);
    int* cand_j = (int*)(ws + BASE + (size_t)nc * KNN * N_PAD * 4);

    sq_kernel<<<dim3((N_NODES + 255) / 256), dim3(256), 0, stream>>>(x, sq);
    knn_partial_kernel<<<dim3((N_NODES + RPB - 1) / RPB, nc), dim3(RPB), 0, stream>>>(
        x, sq, cand_d, cand_j, knn, jchunk, nc);
    if (nc > 1) {
      knn_merge_kernel<<<dim3((N_NODES + 255) / 256), dim3(256), 0, stream>>>(
          cand_d, cand_j, knn, nc);
    }
    mlp_kernel<<<dim3(N_NODES), dim3(HID), 0, stream>>>(x, knn, W1, b1, W2, b2, out);
  }
}